// Round 11
// baseline (88.582 us; speedup 1.0000x reference)
//
#include <hip/hip_runtime.h>

#define HH     256
#define PPITCH 272                    // padded dwords per packed row
#define PPLANE (PPITCH * 272)         // 73984 dwords per (img,batch) plane
#define XOFF   12                     // buffer col of image col 0
#define YOFF   8                      // buffer row of image row 0

__device__ __forceinline__ unsigned sad8(unsigned a, unsigned b, unsigned c) {
  unsigned d;
  asm("v_sad_u8 %0, %1, %2, %3" : "=v"(d) : "v"(a), "v"(b), "v"(c));
  return d;
}
__device__ __forceinline__ unsigned sad32(unsigned a, unsigned b, unsigned c) {
  unsigned d;
  asm("v_sad_u32 %0, %1, %2, %3" : "=v"(d) : "v"(a), "v"(b), "v"(c));
  return d;
}
__device__ __forceinline__ unsigned mad24(unsigned a, unsigned b, unsigned c) {
  unsigned d;
  asm("v_mad_u32_u24 %0, %1, %2, %3" : "=v"(d) : "v"(a), "v"(b), "v"(c));
  return d;
}
__device__ __forceinline__ unsigned q8(float x) {   // round(x*255), x in [0,1)
  return (unsigned)(x * 255.0f + 0.5f);
}

// ---------------- kernel 1: fp32 RGB -> packed u8 RGB0 dword image ----------------
__global__ __launch_bounds__(256, 4)
void pack_kernel(const float* __restrict__ orig, const float* __restrict__ sim,
                 unsigned* __restrict__ wimg) {
  const int id  = blockIdx.x * 256 + threadIdx.x;   // 0 .. 524287
  const int c4  = id & 63;                          // 4-pixel chunk in row
  const int row = (id >> 6) & 255;
  const int b   = (id >> 14) & 15;
  const int img = id >> 18;                         // 0 | 1
  const float* base = (img ? sim : orig) + (size_t)b * 3 * HH * HH
                    + row * HH + c4 * 4;
  float4 va = *(const float4*)(base);
  float4 vb = *(const float4*)(base + HH * HH);
  float4 vc = *(const float4*)(base + 2 * HH * HH);
  uint4 pk;
  pk.x = q8(va.x) | (q8(vb.x) << 8) | (q8(vc.x) << 16);
  pk.y = q8(va.y) | (q8(vb.y) << 8) | (q8(vc.y) << 16);
  pk.z = q8(va.z) | (q8(vb.z) << 8) | (q8(vc.z) << 16);
  pk.w = q8(va.w) | (q8(vb.w) << 8) | (q8(vc.w) << 16);
  *(uint4*)&wimg[(size_t)(img * 16 + b) * PPLANE + (row + YOFF) * PPITCH
                 + XOFF + c4 * 4] = pk;
}

// ---------------- kernel 2: windows via direct (L1-cached) global loads ----------------
// window dword M in [0,15]; target pixel x = xp0 + M - 7; pair (P,J) uses M = P+J+7.
#define LOADW                                                               \
  { const uint4* q0_ = (const uint4*)p0;                                    \
    const uint4* q1_ = (const uint4*)p1;                                    \
    uint4 A_ = q0_[0], B_ = q0_[1], C_ = q0_[2], D_ = q0_[3];               \
    w0[0]=A_.x; w0[1]=A_.y; w0[2]=A_.z; w0[3]=A_.w;                         \
    w0[4]=B_.x; w0[5]=B_.y; w0[6]=B_.z; w0[7]=B_.w;                         \
    w0[8]=C_.x; w0[9]=C_.y; w0[10]=C_.z; w0[11]=C_.w;                       \
    w0[12]=D_.x; w0[13]=D_.y; w0[14]=D_.z; w0[15]=D_.w;                     \
    uint4 E_ = q1_[0], F_ = q1_[1], G_ = q1_[2], I_ = q1_[3];               \
    w1[0]=E_.x; w1[1]=E_.y; w1[2]=E_.z; w1[3]=E_.w;                         \
    w1[4]=F_.x; w1[5]=F_.y; w1[6]=F_.z; w1[7]=F_.w;                         \
    w1[8]=G_.x; w1[9]=G_.y; w1[10]=G_.z; w1[11]=G_.w;                       \
    w1[12]=I_.x; w1[13]=I_.y; w1[14]=I_.z; w1[15]=I_.w; }

#define PF(P, J)                                                            \
  { unsigned so_ = sad8(cen0[P], w0[(P)+(J)+7], zr);                        \
    unsigned ss_ = sad8(cen1[P], w1[(P)+(J)+7], zr);                        \
    acc = sad32(so_, ss_, acc); }
#define PM(P, J)                                                            \
  { unsigned so_ = sad8(cen0[P], w0[(P)+(J)+7], zr);                        \
    unsigned ss_ = sad8(cen1[P], w1[(P)+(J)+7], zr);                        \
    unsigned d_  = sad32(so_, ss_, zr);                                     \
    unsigned w2_ = cenv[P] + (ym & xok[(P)+(J)+7]);                         \
    acc = mad24(d_, w2_, acc); }

#define JF(J) PF(0,J) PF(1,J) PF(2,J) PF(3,J)
#define JM(J) PM(0,J) PM(1,J) PM(2,J) PM(3,J)
#define ROWF JF(-5) JF(-4) JF(-3) JF(-2) JF(-1) JF(0) JF(1) JF(2) JF(3) JF(4) JF(5)
#define ROWM JM(-5) JM(-4) JM(-3) JM(-2) JM(-1) JM(0) JM(1) JM(2) JM(3) JM(4) JM(5)

__global__ __launch_bounds__(256, 2)
void contrast_main(const unsigned* __restrict__ wimg, float* __restrict__ part) {
  const int tid  = threadIdx.x;
  const int lane = tid & 63;
  const int wv   = tid >> 6;
  const int bx = blockIdx.x, by = blockIdx.y, b = blockIdx.z;
  const int lx = lane & 3, ly = lane >> 2;

  const int g   = by * 64 + wv * 16;        // wave row-group base (image coords of ly=0 center +5)
  const int y0  = g + ly - 5;               // center p'_y
  const int xp0 = bx * 16 + 4 * lx - 5;     // center p'_x for P=0

  // buffer address of window dword M=0 (image col xp0-7 -> buffer col bx*16+4*lx)
  const unsigned* p0 = wimg + (size_t)b * PPLANE + (y0 + YOFF) * PPITCH
                     + bx * 16 + 4 * lx;
  const unsigned* p1 = p0 + 16 * PPLANE;    // second image

  unsigned w0[16], w1[16];
  unsigned cen0[4], cen1[4];
  unsigned zr = 0, acc = 0;

  // wave-uniform interior test
  const bool fastw = (bx >= 1) && (bx <= 14) && (g >= 5) && (g <= 230);

  LOADW                                       // window row k=0
  #pragma unroll
  for (int p = 0; p < 4; ++p) { cen0[p] = w0[p + 7]; cen1[p] = w1[p + 7]; }

  float ftot;
  if (fastw) {
    JF(1) JF(2) JF(3) JF(4) JF(5)             // i=0: j=1..5
    #pragma unroll 1
    for (int k = 1; k <= 5; ++k) {
      p0 += PPITCH; p1 += PPITCH;
      LOADW
      ROWF
    }
    ftot = 2.0f * (float)acc;                 // exact: acc < 2^18
  } else {
    unsigned xok[16];
    #pragma unroll
    for (int m = 0; m < 16; ++m)
      xok[m] = ((unsigned)(xp0 + m - 7) < 246u) ? 1u : 0u;
    const unsigned ym0 = ((unsigned)y0 < 246u) ? 1u : 0u;
    unsigned cenv[4];
    #pragma unroll
    for (int p = 0; p < 4; ++p) cenv[p] = ym0 & xok[p + 7];

    unsigned ym = ym0;                        // k=0: target row == center row
    JM(1) JM(2) JM(3) JM(4) JM(5)
    #pragma unroll 1
    for (int k = 1; k <= 5; ++k) {
      p0 += PPITCH; p1 += PPITCH;
      LOADW
      ym = ((unsigned)(y0 + k) < 246u) ? 1u : 0u;
      ROWM
    }
    ftot = (float)acc;                        // exact: acc < 2^19
  }

  // wave-level reduce -> one plain store per wave (no LDS, no barrier, no atomics)
  #pragma unroll
  for (int off = 32; off > 0; off >>= 1)
    ftot += __shfl_down(ftot, off, 64);
  if (lane == 0)
    part[(((b * 4 + by) * 16 + bx) << 2) + wv] = ftot;
}

// ---------------- kernel 3: 4096 partials -> scalar ----------------
__global__ __launch_bounds__(256, 1)
void reduce_kernel(const float* __restrict__ part, float* __restrict__ out) {
  __shared__ float ws4[4];
  const int tid = threadIdx.x;
  const float4* p4 = (const float4*)part + tid * 4;
  float4 a = p4[0], c = p4[1], d = p4[2], e = p4[3];
  float s = ((a.x + a.y) + (a.z + a.w)) + ((c.x + c.y) + (c.z + c.w))
          + ((d.x + d.y) + (d.z + d.w)) + ((e.x + e.y) + (e.z + e.w));
  #pragma unroll
  for (int off = 32; off > 0; off >>= 1)
    s += __shfl_down(s, off, 64);
  if ((tid & 63) == 0) ws4[tid >> 6] = s;
  __syncthreads();
  if (tid == 0) {
    const float scale = (1.0f / 255.0f) / 116190720.0f;   // dequant + mean
    out[0] = (ws4[0] + ws4[1] + ws4[2] + ws4[3]) * scale;
  }
}

extern "C" void kernel_launch(void* const* d_in, const int* in_sizes, int n_in,
                              void* d_out, int out_size, void* d_ws, size_t ws_size,
                              hipStream_t stream) {
  (void)in_sizes; (void)n_in; (void)ws_size; (void)out_size;
  const float* orig = (const float*)d_in[0];
  const float* sim  = (const float*)d_in[1];
  float* out = (float*)d_out;

  unsigned* wimg = (unsigned*)d_ws;                 // 32 planes x 73984 dwords = 9.47 MB
  float*    part = (float*)d_ws + 32 * PPLANE;      // 4096 floats after the planes

  hipLaunchKernelGGL(pack_kernel, dim3(2048), dim3(256), 0, stream, orig, sim, wimg);
  hipLaunchKernelGGL(contrast_main, dim3(16, 4, 16), dim3(256), 0, stream, wimg, part);
  hipLaunchKernelGGL(reduce_kernel, dim3(1), dim3(256), 0, stream, part, out);
}

// Round 12
// 87.842 us; speedup vs baseline: 1.0084x; 1.0084x over previous
//
#include <hip/hip_runtime.h>

#define HH     256
#define PPITCH 280                    // dwords per packed row
#define PROWS  272
#define PPLANE (PPITCH * PROWS)       // 76160 dwords per (img,batch) plane
#define XOFF   12                     // buffer col of pixel col 0 (4-aligned for pack)
#define YOFF   5                      // buffer row of pixel row 0

__device__ __forceinline__ unsigned sad8(unsigned a, unsigned b, unsigned c) {
  unsigned d;
  asm("v_sad_u8 %0, %1, %2, %3" : "=v"(d) : "v"(a), "v"(b), "v"(c));
  return d;
}
__device__ __forceinline__ unsigned sad32(unsigned a, unsigned b, unsigned c) {
  unsigned d;
  asm("v_sad_u32 %0, %1, %2, %3" : "=v"(d) : "v"(a), "v"(b), "v"(c));
  return d;
}
__device__ __forceinline__ unsigned mad24(unsigned a, unsigned b, unsigned c) {
  unsigned d;
  asm("v_mad_u32_u24 %0, %1, %2, %3" : "=v"(d) : "v"(a), "v"(b), "v"(c));
  return d;
}
__device__ __forceinline__ unsigned q8(float x) { return (unsigned)(x * 255.0f + 0.5f); }
__device__ __forceinline__ unsigned eld(uint4 v, int k) {
  return k == 0 ? v.x : k == 1 ? v.y : k == 2 ? v.z : v.w;
}
#define ELD(ARR, M) eld(ARR[(M) >> 2], (M) & 3)

// ---------------- kernel 1: fp32 RGB -> packed u8 RGB0 dword image ----------------
__global__ __launch_bounds__(256, 4)
void pack_kernel(const float* __restrict__ orig, const float* __restrict__ sim,
                 unsigned* __restrict__ wimg) {
  const int id  = blockIdx.x * 256 + threadIdx.x;   // 0 .. 524287
  const int c4  = id & 63;
  const int row = (id >> 6) & 255;
  const int b   = (id >> 14) & 15;
  const int img = id >> 18;
  const float* base = (img ? sim : orig) + (size_t)b * 3 * HH * HH + row * HH + c4 * 4;
  float4 va = *(const float4*)(base);
  float4 vb = *(const float4*)(base + HH * HH);
  float4 vc = *(const float4*)(base + 2 * HH * HH);
  uint4 pk;
  pk.x = q8(va.x) | (q8(vb.x) << 8) | (q8(vc.x) << 16);
  pk.y = q8(va.y) | (q8(vb.y) << 8) | (q8(vc.y) << 16);
  pk.z = q8(va.z) | (q8(vb.z) << 8) | (q8(vc.z) << 16);
  pk.w = q8(va.w) | (q8(vb.w) << 8) | (q8(vc.w) << 16);
  wimg += (size_t)(img * 16 + b) * PPLANE + (row + YOFF) * PPITCH + XOFF + 4 * c4;
  *(uint4*)wimg = pk;
}

// ---------------- kernel 2: direct-load main with A/B pipelined rows ----------------
// window dword M in [0,23] <-> pixel col xp0 - 3 + M; pair (P,J): M = P+J+8; cen: M = P+8
#define LOADR(S, RP)                                                        \
  { const uint4* q0_ = (const uint4*)(RP);                                  \
    const uint4* q1_ = (const uint4*)((RP) + 16 * PPLANE);                  \
    S##0[0]=q0_[0]; S##0[1]=q0_[1]; S##0[2]=q0_[2];                         \
    S##0[3]=q0_[3]; S##0[4]=q0_[4]; S##0[5]=q0_[5];                         \
    S##1[0]=q1_[0]; S##1[1]=q1_[1]; S##1[2]=q1_[2];                         \
    S##1[3]=q1_[3]; S##1[4]=q1_[4]; S##1[5]=q1_[5]; }

#define PF(S, P, J)                                                         \
  { unsigned so_ = sad8(cen0[P], ELD(S##0, (P)+(J)+8), zr);                 \
    unsigned ss_ = sad8(cen1[P], ELD(S##1, (P)+(J)+8), zr);                 \
    acc = sad32(so_, ss_, acc); }
#define PM(S, P, J)                                                         \
  { unsigned so_ = sad8(cen0[P], ELD(S##0, (P)+(J)+8), zr);                 \
    unsigned ss_ = sad8(cen1[P], ELD(S##1, (P)+(J)+8), zr);                 \
    unsigned d_  = sad32(so_, ss_, zr);                                     \
    unsigned w2_ = cenv[P] + (ym & xok[(P)+(J)+8]);                         \
    acc = mad24(d_, w2_, acc); }

#define JF(S,J) PF(S,0,J) PF(S,1,J) PF(S,2,J) PF(S,3,J)                     \
                PF(S,4,J) PF(S,5,J) PF(S,6,J) PF(S,7,J)
#define JM(S,J) PM(S,0,J) PM(S,1,J) PM(S,2,J) PM(S,3,J)                     \
                PM(S,4,J) PM(S,5,J) PM(S,6,J) PM(S,7,J)
#define ROWF(S) JF(S,-5) JF(S,-4) JF(S,-3) JF(S,-2) JF(S,-1) JF(S,0)        \
                JF(S,1) JF(S,2) JF(S,3) JF(S,4) JF(S,5)
#define ROWM(S) JM(S,-5) JM(S,-4) JM(S,-3) JM(S,-2) JM(S,-1) JM(S,0)        \
                JM(S,1) JM(S,2) JM(S,3) JM(S,4) JM(S,5)

__global__ __launch_bounds__(256, 2)
void contrast_main(const unsigned* __restrict__ wimg, float* __restrict__ out) {
  __shared__ float wsum[4];
  const int tid = threadIdx.x, lane = tid & 63, wv = tid >> 6;
  const int bx = blockIdx.x, by = blockIdx.y, b = blockIdx.z;
  const int lx = lane & 3, ly = lane >> 2;

  const int G   = by * 64 + wv * 16;
  const int y0  = G + ly - 5;               // output row p'_y
  const int xp0 = bx * 32 + 8 * lx - 5;     // output col p'_x for P=0

  // row k load base: pixel row y0+5+k, window col base pixel xp0-3 -> buffer col bx*32+8lx+4
  const unsigned* rp = wimg + (size_t)b * PPLANE + (y0 + 5 + YOFF) * PPITCH
                     + bx * 32 + 8 * lx + 4;

  uint4 A0[6], A1[6], B0[6], B1[6];
  unsigned cen0[8], cen1[8];
  unsigned zr = 0, acc = 0;

  const bool fastw = (bx >= 1) && (bx <= 6) && (G >= 16) && (G <= 224);

  LOADR(A, rp)                              // row k=0  (pixel row y0+5)
  LOADR(B, rp + PPITCH)                     // row k=1
  #pragma unroll
  for (int p = 0; p < 8; ++p) { cen0[p] = ELD(A0, p + 8); cen1[p] = ELD(A1, p + 8); }

  float ftot;
  if (fastw) {
    JF(A,1) JF(A,2) JF(A,3) JF(A,4) JF(A,5)          // k=0: j=1..5
    const unsigned* pA = rp;
    const unsigned* pB = rp + PPITCH;
    #pragma unroll 1
    for (int t = 0; t < 2; ++t) {
      pA += 2 * PPITCH;
      LOADR(A, pA)                                   // row 2t+2 in flight
      ROWF(B)                                        // row 2t+1
      pB += 2 * PPITCH;
      LOADR(B, pB)                                   // row 2t+3 in flight
      ROWF(A)                                        // row 2t+2
    }
    ROWF(B)                                          // row 5
    ftot = 2.0f * (float)acc;                        // exact: acc < 2^21
  } else {
    unsigned xok[24];
    #pragma unroll
    for (int m = 0; m < 24; ++m)
      xok[m] = ((unsigned)(xp0 + m - 8) < 246u) ? 1u : 0u;
    const unsigned ym0v = ((unsigned)y0 < 246u) ? 1u : 0u;
    unsigned cenv[8];
    #pragma unroll
    for (int p = 0; p < 8; ++p) cenv[p] = ym0v & xok[p + 8];

    unsigned ym = ym0v;                              // k=0 target row == center row
    JM(A,1) JM(A,2) JM(A,3) JM(A,4) JM(A,5)
    const unsigned* pA = rp;
    const unsigned* pB = rp + PPITCH;
    #pragma unroll 1
    for (int t = 0; t < 2; ++t) {
      pA += 2 * PPITCH;
      LOADR(A, pA)
      ym = ((unsigned)(y0 + 2 * t + 1) < 246u) ? 1u : 0u;
      ROWM(B)
      pB += 2 * PPITCH;
      LOADR(B, pB)
      ym = ((unsigned)(y0 + 2 * t + 2) < 246u) ? 1u : 0u;
      ROWM(A)
    }
    ym = ((unsigned)(y0 + 5) < 246u) ? 1u : 0u;
    ROWM(B)
    ftot = (float)acc;                               // exact: acc < 2^22
  }

  // ---- reduce: wave shuffle -> LDS -> one atomic per block ----
  #pragma unroll
  for (int off = 32; off > 0; off >>= 1)
    ftot += __shfl_down(ftot, off, 64);
  if (lane == 0) wsum[wv] = ftot;
  __syncthreads();
  if (tid == 0) {
    const float scale = (1.0f / 255.0f) / 116190720.0f;   // dequant + mean
    atomicAdd(out, (wsum[0] + wsum[1] + wsum[2] + wsum[3]) * scale);
  }
}

extern "C" void kernel_launch(void* const* d_in, const int* in_sizes, int n_in,
                              void* d_out, int out_size, void* d_ws, size_t ws_size,
                              hipStream_t stream) {
  (void)in_sizes; (void)n_in; (void)ws_size; (void)out_size;
  const float* orig = (const float*)d_in[0];
  const float* sim  = (const float*)d_in[1];
  float* out = (float*)d_out;
  unsigned* wimg = (unsigned*)d_ws;        // 32 planes x 76160 dwords = 9.75 MB

  hipMemsetAsync(out, 0, sizeof(float), stream);
  hipLaunchKernelGGL(pack_kernel, dim3(2048), dim3(256), 0, stream, orig, sim, wimg);
  hipLaunchKernelGGL(contrast_main, dim3(8, 4, 16), dim3(256), 0, stream, wimg, out);
}